// Round 1
// baseline (203.309 us; speedup 1.0000x reference)
//
#include <hip/hip_runtime.h>
#include <hip/hip_bf16.h>
#include <hip/hip_fp16.h>

typedef __attribute__((ext_vector_type(8))) short bf16x8;
typedef __attribute__((ext_vector_type(4))) float f32x4;

__device__ __forceinline__ unsigned short f2bf(float f) {
    unsigned u = __float_as_uint(f);
    u += 0x7fffu + ((u >> 16) & 1u);
    return (unsigned short)(u >> 16);
}

#define GLOAD_LDS16(g, l)                                                           \
    __builtin_amdgcn_global_load_lds(                                               \
        (const __attribute__((address_space(1))) void*)(g),                         \
        (__attribute__((address_space(3))) void*)(l), 16, 0, 0)

#define BM 128
#define BN 128
#define BK 32

// C = A * B^T : A[M][K] bf16(row-major), B[N][K] bf16(row-major).
// OMODE 0: C bf16; 1: C f32; 2: C f16 scaled by 1/32.
// causal: limit K-loop to K-tiles <= (bm+1)*BM (A is lower-triangular-banded: P)
template <int OMODE>
__global__ __launch_bounds__(256) void gemm_bt(
    const unsigned short* __restrict__ A, const unsigned short* __restrict__ B,
    void* __restrict__ Cv, int M, int N, int K,
    long long sA, long long sB, long long sC, int causal) {
    __shared__ unsigned short As[2][BM * BK];
    __shared__ unsigned short Bs[2][BN * BK];

    const int bz = blockIdx.z;
    A += (size_t)bz * (size_t)sA;
    B += (size_t)bz * (size_t)sB;

    const int bm = blockIdx.x, bn = blockIdx.y;
    const int tid = threadIdx.x;
    const int wid = tid >> 6;
    const int lane = tid & 63;
    const int wr = wid >> 1, wc = wid & 1;
    const int frow = lane & 15;
    const int kgrp = lane >> 4;

    int nt = K / BK;
    if (causal) {
        int lim = (bm + 1) * (BM / BK);
        if (lim < nt) nt = lim;
    }

    const int c0 = (wid * 2 + 0) * 64 + lane;  // staging chunk ids (16B each)
    const int c1 = (wid * 2 + 1) * 64 + lane;
    const unsigned short* Abase = A + (size_t)(bm * BM) * K;
    const unsigned short* Bbase = B + (size_t)(bn * BN) * K;

    auto STAGE = [&](int kt, int buf) {
        const unsigned short* Ag = Abase + kt * BK;
        const unsigned short* Bg = Bbase + kt * BK;
        GLOAD_LDS16(Ag + (size_t)(c0 >> 2) * K + (c0 & 3) * 8,
                    (char*)&As[buf][0] + (wid * 2 + 0) * 1024);
        GLOAD_LDS16(Bg + (size_t)(c0 >> 2) * K + (c0 & 3) * 8,
                    (char*)&Bs[buf][0] + (wid * 2 + 0) * 1024);
        GLOAD_LDS16(Ag + (size_t)(c1 >> 2) * K + (c1 & 3) * 8,
                    (char*)&As[buf][0] + (wid * 2 + 1) * 1024);
        GLOAD_LDS16(Bg + (size_t)(c1 >> 2) * K + (c1 & 3) * 8,
                    (char*)&Bs[buf][0] + (wid * 2 + 1) * 1024);
    };

    f32x4 acc[4][4];
#pragma unroll
    for (int mi = 0; mi < 4; ++mi)
#pragma unroll
        for (int ni = 0; ni < 4; ++ni) acc[mi][ni] = (f32x4){0.f, 0.f, 0.f, 0.f};

    STAGE(0, 0);
    __syncthreads();

    for (int kt = 0; kt < nt; ++kt) {
        const int buf = kt & 1;
        if (kt + 1 < nt) STAGE(kt + 1, buf ^ 1);
        bf16x8 af[4], bfr[4];
#pragma unroll
        for (int mi = 0; mi < 4; ++mi) {
            int row = wr * 64 + mi * 16 + frow;
            af[mi] = *(const bf16x8*)&As[buf][row * BK + kgrp * 8];
        }
#pragma unroll
        for (int ni = 0; ni < 4; ++ni) {
            int col = wc * 64 + ni * 16 + frow;
            bfr[ni] = *(const bf16x8*)&Bs[buf][col * BK + kgrp * 8];
        }
#pragma unroll
        for (int mi = 0; mi < 4; ++mi)
#pragma unroll
            for (int ni = 0; ni < 4; ++ni)
                acc[mi][ni] = __builtin_amdgcn_mfma_f32_16x16x32_bf16(
                    af[mi], bfr[ni], acc[mi][ni], 0, 0, 0);
        __syncthreads();
    }

    // epilogue: D row = kgrp*4 + r, col = frow (within 16x16 fragment)
    const size_t row0 = (size_t)bm * BM + wr * 64 + kgrp * 4;
    const int col0 = bn * BN + wc * 64 + frow;
    if (OMODE == 1) {
        float* Cp = (float*)Cv + (size_t)bz * (size_t)sC;
#pragma unroll
        for (int mi = 0; mi < 4; ++mi)
#pragma unroll
            for (int r = 0; r < 4; ++r) {
                float* op = Cp + (row0 + mi * 16 + r) * N + col0;
#pragma unroll
                for (int ni = 0; ni < 4; ++ni) op[ni * 16] = acc[mi][ni][r];
            }
    } else if (OMODE == 0) {
        unsigned short* Cp = (unsigned short*)Cv + (size_t)bz * (size_t)sC;
#pragma unroll
        for (int mi = 0; mi < 4; ++mi)
#pragma unroll
            for (int r = 0; r < 4; ++r) {
                unsigned short* op = Cp + (row0 + mi * 16 + r) * N + col0;
#pragma unroll
                for (int ni = 0; ni < 4; ++ni) op[ni * 16] = f2bf(acc[mi][ni][r]);
            }
    } else {
        unsigned short* Cp = (unsigned short*)Cv + (size_t)bz * (size_t)sC;
#pragma unroll
        for (int mi = 0; mi < 4; ++mi)
#pragma unroll
            for (int r = 0; r < 4; ++r) {
                unsigned short* op = Cp + (row0 + mi * 16 + r) * N + col0;
#pragma unroll
                for (int ni = 0; ni < 4; ++ni)
                    op[ni * 16] =
                        __half_as_ushort(__float2half(acc[mi][ni][r] * 0.03125f));
            }
    }
}

__global__ __launch_bounds__(256) void cvt_f32_bf16(
    const float* __restrict__ in, unsigned short* __restrict__ out, int n) {
    int idx = blockIdx.x * blockDim.x + threadIdx.x;
    int stride = gridDim.x * blockDim.x;
    for (int i = idx * 4; i < n; i += stride * 4) {
        float4 v = *(const float4*)(in + i);
        ushort4 o;
        o.x = f2bf(v.x); o.y = f2bf(v.y); o.z = f2bf(v.z); o.w = f2bf(v.w);
        *(ushort4*)(out + i) = o;
    }
}

// out[n][k] = (bf16) in[k][n];  in: [Kd][Nd] f32
__global__ __launch_bounds__(256) void transpose_cvt_w(
    const float* __restrict__ in, unsigned short* __restrict__ out, int Kd, int Nd) {
    __shared__ float t[32][33];
    const int tr = blockIdx.y * 32, tc = blockIdx.x * 32;
    const int r = threadIdx.x >> 3, c4 = (threadIdx.x & 7) * 4;
    float4 v = *(const float4*)&in[(size_t)(tr + r) * Nd + tc + c4];
    t[r][c4 + 0] = v.x; t[r][c4 + 1] = v.y; t[r][c4 + 2] = v.z; t[r][c4 + 3] = v.w;
    __syncthreads();
    ushort4 o;
    o.x = f2bf(t[c4 + 0][r]); o.y = f2bf(t[c4 + 1][r]);
    o.z = f2bf(t[c4 + 2][r]); o.w = f2bf(t[c4 + 3][r]);
    *(ushort4*)&out[(size_t)(tc + r) * Kd + tr + c4] = o;
}

// out[c][r] = in[r][c], bf16, batched by blockIdx.z
__global__ __launch_bounds__(256) void transpose_bf16(
    const unsigned short* __restrict__ in, unsigned short* __restrict__ out,
    int R, int Cc) {
    __shared__ unsigned short t[32][36];
    const int bz = blockIdx.z;
    in += (size_t)bz * R * Cc;
    out += (size_t)bz * R * Cc;
    const int tr = blockIdx.y * 32, tc = blockIdx.x * 32;
    const int r = threadIdx.x >> 3, c4 = (threadIdx.x & 7) * 4;
    ushort4 v = *(const ushort4*)&in[(size_t)(tr + r) * Cc + tc + c4];
    t[r][c4 + 0] = v.x; t[r][c4 + 1] = v.y; t[r][c4 + 2] = v.z; t[r][c4 + 3] = v.w;
    __syncthreads();
    ushort4 o;
    o.x = t[c4 + 0][r]; o.y = t[c4 + 1][r]; o.z = t[c4 + 2][r]; o.w = t[c4 + 3][r];
    *(ushort4*)&out[(size_t)(tc + r) * R + tr + c4] = o;
}

// In-place: read fp16 scores row, softmax over FULL row, causal-mask, write bf16 P.
__global__ __launch_bounds__(256) void softmax_mask(unsigned short* S, int Sd) {
    const int i = blockIdx.x;  // query row
    const int b = blockIdx.y;
    unsigned short* row = S + ((size_t)b * Sd + (size_t)i) * Sd;
    const int t = threadIdx.x;
    const int lane = t & 63, wid = t >> 6;

    ushort4 h0 = *(const ushort4*)(row + t * 8);
    ushort4 h1 = *(const ushort4*)(row + t * 8 + 4);
    float v[8];
    v[0] = __half2float(__ushort_as_half(h0.x));
    v[1] = __half2float(__ushort_as_half(h0.y));
    v[2] = __half2float(__ushort_as_half(h0.z));
    v[3] = __half2float(__ushort_as_half(h0.w));
    v[4] = __half2float(__ushort_as_half(h1.x));
    v[5] = __half2float(__ushort_as_half(h1.y));
    v[6] = __half2float(__ushort_as_half(h1.z));
    v[7] = __half2float(__ushort_as_half(h1.w));

    float m = v[0];
#pragma unroll
    for (int j = 1; j < 8; ++j) m = fmaxf(m, v[j]);
#pragma unroll
    for (int o = 32; o; o >>= 1) m = fmaxf(m, __shfl_xor(m, o));
    __shared__ float redm[4];
    __shared__ float reds[4];
    if (lane == 0) redm[wid] = m;
    __syncthreads();
    m = fmaxf(fmaxf(redm[0], redm[1]), fmaxf(redm[2], redm[3]));

    float e[8], s = 0.f;
#pragma unroll
    for (int j = 0; j < 8; ++j) {
        e[j] = __expf(v[j] - m);
        s += e[j];
    }
#pragma unroll
    for (int o = 32; o; o >>= 1) s += __shfl_xor(s, o);
    if (lane == 0) reds[wid] = s;
    __syncthreads();
    s = reds[0] + reds[1] + reds[2] + reds[3];
    const float rinv = 1.0f / s;

    const int base = t * 8;
    ushort4 o0, o1;
    o0.x = (base + 0 <= i) ? f2bf(e[0] * rinv) : 0;
    o0.y = (base + 1 <= i) ? f2bf(e[1] * rinv) : 0;
    o0.z = (base + 2 <= i) ? f2bf(e[2] * rinv) : 0;
    o0.w = (base + 3 <= i) ? f2bf(e[3] * rinv) : 0;
    o1.x = (base + 4 <= i) ? f2bf(e[4] * rinv) : 0;
    o1.y = (base + 5 <= i) ? f2bf(e[5] * rinv) : 0;
    o1.z = (base + 6 <= i) ? f2bf(e[6] * rinv) : 0;
    o1.w = (base + 7 <= i) ? f2bf(e[7] * rinv) : 0;
    *(ushort4*)(row + t * 8) = o0;
    *(ushort4*)(row + t * 8 + 4) = o1;
}

extern "C" void kernel_launch(void* const* d_in, const int* in_sizes, int n_in,
                              void* d_out, int out_size, void* d_ws, size_t ws_size,
                              hipStream_t stream) {
    const int B = 4, S = 2048, D = 1024;
    const size_t M = (size_t)B * S;  // 8192

    const float* x = (const float*)d_in[0];
    const float* Wq = (const float*)d_in[1];
    const float* Wk = (const float*)d_in[2];
    const float* Wv = (const float*)d_in[3];
    float* out = (float*)d_out;

    unsigned short* xb = (unsigned short*)d_ws;        // M*D
    unsigned short* Wt = xb + M * D;                   // 3*D*D
    unsigned short* Qb = Wt + 3 * (size_t)D * D;       // M*D
    unsigned short* Kb = Qb + M * D;                   // M*D
    unsigned short* Vb = Kb + M * D;                   // M*D
    unsigned short* Vt = Vb + M * D;                   // M*D
    unsigned short* Sc = Vt + M * D;                   // B*S*S
    const size_t need = (size_t)(M * D * 5 + 3 * (size_t)D * D + (size_t)B * S * S) * 2;
    if (ws_size < need) return;  // fail loudly (output stays poisoned)

    cvt_f32_bf16<<<2048, 256, 0, stream>>>(x, xb, (int)(M * D));
    dim3 tg(D / 32, D / 32);
    transpose_cvt_w<<<tg, 256, 0, stream>>>(Wq, Wt + 0 * (size_t)D * D, D, D);
    transpose_cvt_w<<<tg, 256, 0, stream>>>(Wk, Wt + 1 * (size_t)D * D, D, D);
    transpose_cvt_w<<<tg, 256, 0, stream>>>(Wv, Wt + 2 * (size_t)D * D, D, D);

    // Q,K,V projections: z=3 over {Wq,Wk,Wv}; same A (strideA=0)
    gemm_bt<0><<<dim3(M / BM, D / BN, 3), 256, 0, stream>>>(
        xb, Wt, (void*)Qb, (int)M, D, D, 0LL, (long long)D * D, (long long)(M * D), 0);

    transpose_bf16<<<dim3(D / 32, S / 32, B), 256, 0, stream>>>(Vb, Vt, S, D);

    // scores = Q K^T / 32 -> fp16
    gemm_bt<2><<<dim3(S / BM, S / BN, B), 256, 0, stream>>>(
        Qb, Kb, (void*)Sc, S, S, D, (long long)S * D, (long long)S * D,
        (long long)S * S, 0);

    softmax_mask<<<dim3(S, B), 256, 0, stream>>>(Sc, S);

    // context = P @ V  (A = P bf16, B = Vt[D][S]), causal K-tile skip
    gemm_bt<1><<<dim3(S / BM, D / BN, B), 256, 0, stream>>>(
        Sc, Vt, (void*)out, S, D, S, (long long)S * S, (long long)D * S,
        (long long)S * D, 1);
}

// Round 2
// 181.681 us; speedup vs baseline: 1.1190x; 1.1190x over previous
//
#include <hip/hip_runtime.h>
#include <hip/hip_bf16.h>
#include <hip/hip_fp16.h>

typedef __attribute__((ext_vector_type(8))) short bf16x8;
typedef __attribute__((ext_vector_type(4))) float f32x4;

__device__ __forceinline__ unsigned short f2bf(float f) {
    unsigned u = __float_as_uint(f);
    u += 0x7fffu + ((u >> 16) & 1u);
    return (unsigned short)(u >> 16);
}

#define GLOAD_LDS16(g, l)                                                           \
    __builtin_amdgcn_global_load_lds(                                               \
        (const __attribute__((address_space(1))) void*)(g),                         \
        (__attribute__((address_space(3))) void*)(l), 16, 0, 0)

// =====================================================================
// 256x256 deep-pipelined GEMM, BK=64, 8 waves (2Mx4N), counted vmcnt.
// C = A * B^T : A[M][K] bf16, B[N][K] bf16 row-major.
// OMODE 0: C bf16; 2: C f16 scaled by 1/32.
// LDS: 2 dbuf x 4 halves (A0,A1,B0,B1) x [128][64] bf16 = 128 KiB.
// Swizzle: 16B-chunk index ^= (row&7); applied on global SOURCE during
// staging (gload_lds dest linear) and on ds_read addresses.
// =====================================================================
#define TBM 256
#define TBN 256
#define TBK 64

template <int OMODE>
__global__ __launch_bounds__(512, 2) void gemm256(
    const unsigned short* __restrict__ A, const unsigned short* __restrict__ B,
    void* __restrict__ Cv, int M, int N, int K,
    long long sA, long long sB, long long sC) {
    __shared__ unsigned short lds[2][4][128 * 64];

    const int bz = blockIdx.z;
    A += (size_t)bz * (size_t)sA;
    B += (size_t)bz * (size_t)sB;

    const int bm = blockIdx.x, bn = blockIdx.y;
    const int tid = threadIdx.x;
    const int wid = tid >> 6, lane = tid & 63;
    const int wr = wid >> 2, wc = wid & 3;       // 2 x 4 wave grid
    const int frow = lane & 15, kgrp = lane >> 4;
    const int nt = K / TBK;

    const unsigned short* Abase = A + (size_t)(bm * TBM) * K;
    const unsigned short* Bbase = B + (size_t)(bn * TBN) * K;

    // stage one 128x64 half-tile: 2 x gload_lds(16B) per thread.
    auto STAGE_H = [&](const unsigned short* gtb, int kt, unsigned short* dsthalf) {
#pragma unroll
        for (int ld = 0; ld < 2; ++ld) {
            const int c = tid + ld * 512;
            const int row = c >> 3, c8 = c & 7;
            GLOAD_LDS16(gtb + (size_t)row * K + kt * TBK + ((c8 ^ (row & 7)) << 3),
                        (char*)dsthalf + ld * 8192 + wid * 1024);
        }
    };

    f32x4 acc[8][4];
#pragma unroll
    for (int i = 0; i < 8; ++i)
#pragma unroll
        for (int j = 0; j < 4; ++j) acc[i][j] = (f32x4){0.f, 0.f, 0.f, 0.f};

    // prologue: tile 0 -> buf 0  (8 loads in flight)
    STAGE_H(Bbase, 0, &lds[0][2][0]);
    STAGE_H(Bbase + 128 * (size_t)K, 0, &lds[0][3][0]);
    STAGE_H(Abase, 0, &lds[0][0][0]);
    STAGE_H(Abase + 128 * (size_t)K, 0, &lds[0][1][0]);

    for (int t = 0; t < nt; ++t) {
        const int buf = t & 1, bufN = buf ^ 1;
        const unsigned short* Ah = &lds[buf][wr][0];
        const unsigned short* Bh = &lds[buf][2 + (wc >> 1)][0];

        // ---- phase 1: stage next B halves, counted wait, barrier ----
        if (t + 1 < nt) {
            STAGE_H(Bbase, t + 1, &lds[bufN][2][0]);
            STAGE_H(Bbase + 128 * (size_t)K, t + 1, &lds[bufN][3][0]);
            asm volatile("s_waitcnt vmcnt(4)" ::: "memory");
        } else {
            asm volatile("s_waitcnt vmcnt(0)" ::: "memory");
        }
        __builtin_amdgcn_s_barrier();

        // B fragments for the whole K-tile (held in regs across phases)
        bf16x8 bfrag[4][2];
#pragma unroll
        for (int n = 0; n < 4; ++n) {
            const int rB = (wc & 1) * 64 + n * 16 + frow;
            const int sw = (rB & 7) << 3;
#pragma unroll
            for (int kk = 0; kk < 2; ++kk)
                bfrag[n][kk] =
                    *(const bf16x8*)&Bh[rB * 64 + ((((kk << 2) + kgrp) << 3) ^ sw)];
        }
        {
            bf16x8 afrag[2][2];
#pragma unroll
            for (int m2 = 0; m2 < 2; ++m2) {
                const int rA = m2 * 16 + frow;
                const int sw = (rA & 7) << 3;
#pragma unroll
                for (int kk = 0; kk < 2; ++kk)
                    afrag[m2][kk] =
                        *(const bf16x8*)&Ah[rA * 64 + ((((kk << 2) + kgrp) << 3) ^ sw)];
            }
            __builtin_amdgcn_s_setprio(1);
#pragma unroll
            for (int m2 = 0; m2 < 2; ++m2)
#pragma unroll
                for (int n = 0; n < 4; ++n)
#pragma unroll
                    for (int kk = 0; kk < 2; ++kk)
                        acc[m2][n] = __builtin_amdgcn_mfma_f32_16x16x32_bf16(
                            afrag[m2][kk], bfrag[n][kk], acc[m2][n], 0, 0, 0);
            __builtin_amdgcn_s_setprio(0);
        }

        // ---- phases 2..4: stage next A halves, compute bands 1..3 ----
#pragma unroll
        for (int q = 1; q < 4; ++q) {
            if (q == 1 && t + 1 < nt) STAGE_H(Abase, t + 1, &lds[bufN][0][0]);
            if (q == 2 && t + 1 < nt)
                STAGE_H(Abase + 128 * (size_t)K, t + 1, &lds[bufN][1][0]);
            bf16x8 afrag[2][2];
#pragma unroll
            for (int m2 = 0; m2 < 2; ++m2) {
                const int rA = q * 32 + m2 * 16 + frow;
                const int sw = (rA & 7) << 3;
#pragma unroll
                for (int kk = 0; kk < 2; ++kk)
                    afrag[m2][kk] =
                        *(const bf16x8*)&Ah[rA * 64 + ((((kk << 2) + kgrp) << 3) ^ sw)];
            }
            __builtin_amdgcn_s_setprio(1);
#pragma unroll
            for (int m2 = 0; m2 < 2; ++m2)
#pragma unroll
                for (int n = 0; n < 4; ++n)
#pragma unroll
                    for (int kk = 0; kk < 2; ++kk)
                        acc[q * 2 + m2][n] = __builtin_amdgcn_mfma_f32_16x16x32_bf16(
                            afrag[m2][kk], bfrag[n][kk], acc[q * 2 + m2][n], 0, 0, 0);
            __builtin_amdgcn_s_setprio(0);
        }
    }

    // epilogue: wave rows wr*128 + mi*16 + kgrp*4 + rr ; cols wc*64 + n*16 + frow
    const size_t row0 = (size_t)bm * TBM + wr * 128 + kgrp * 4;
    const int col0 = bn * TBN + wc * 64 + frow;
    if (OMODE == 0) {
        unsigned short* Cp = (unsigned short*)Cv + (size_t)bz * (size_t)sC;
#pragma unroll
        for (int mi = 0; mi < 8; ++mi)
#pragma unroll
            for (int rr = 0; rr < 4; ++rr) {
                unsigned short* op = Cp + (row0 + mi * 16 + rr) * N + col0;
#pragma unroll
                for (int n = 0; n < 4; ++n) op[n * 16] = f2bf(acc[mi][n][rr]);
            }
    } else {
        unsigned short* Cp = (unsigned short*)Cv + (size_t)bz * (size_t)sC;
#pragma unroll
        for (int mi = 0; mi < 8; ++mi)
#pragma unroll
            for (int rr = 0; rr < 4; ++rr) {
                unsigned short* op = Cp + (row0 + mi * 16 + rr) * N + col0;
#pragma unroll
                for (int n = 0; n < 4; ++n)
                    op[n * 16] =
                        __half_as_ushort(__float2half(acc[mi][n][rr] * 0.03125f));
            }
    }
}

// =====================================================================
// 128x128 m97-style GEMM (kept for causal PV). C f32. causal: skip
// K-tiles beyond the diagonal (A = P is lower-triangular-banded).
// =====================================================================
#define BM 128
#define BN 128
#define BK 32

__global__ __launch_bounds__(256) void gemm_bt_f32(
    const unsigned short* __restrict__ A, const unsigned short* __restrict__ B,
    float* __restrict__ C, int M, int N, int K,
    long long sA, long long sB, long long sC, int causal) {
    __shared__ unsigned short As[2][BM * BK];
    __shared__ unsigned short Bs[2][BN * BK];

    const int bz = blockIdx.z;
    A += (size_t)bz * (size_t)sA;
    B += (size_t)bz * (size_t)sB;

    const int bm = blockIdx.x, bn = blockIdx.y;
    const int tid = threadIdx.x;
    const int wid = tid >> 6;
    const int lane = tid & 63;
    const int wr = wid >> 1, wc = wid & 1;
    const int frow = lane & 15;
    const int kgrp = lane >> 4;

    int nt = K / BK;
    if (causal) {
        int lim = (bm + 1) * (BM / BK);
        if (lim < nt) nt = lim;
    }

    const int c0 = (wid * 2 + 0) * 64 + lane;
    const int c1 = (wid * 2 + 1) * 64 + lane;
    const unsigned short* Abase = A + (size_t)(bm * BM) * K;
    const unsigned short* Bbase = B + (size_t)(bn * BN) * K;

    auto STAGE = [&](int kt, int buf) {
        const unsigned short* Ag = Abase + kt * BK;
        const unsigned short* Bg = Bbase + kt * BK;
        GLOAD_LDS16(Ag + (size_t)(c0 >> 2) * K + (c0 & 3) * 8,
                    (char*)&As[buf][0] + (wid * 2 + 0) * 1024);
        GLOAD_LDS16(Bg + (size_t)(c0 >> 2) * K + (c0 & 3) * 8,
                    (char*)&Bs[buf][0] + (wid * 2 + 0) * 1024);
        GLOAD_LDS16(Ag + (size_t)(c1 >> 2) * K + (c1 & 3) * 8,
                    (char*)&As[buf][0] + (wid * 2 + 1) * 1024);
        GLOAD_LDS16(Bg + (size_t)(c1 >> 2) * K + (c1 & 3) * 8,
                    (char*)&Bs[buf][0] + (wid * 2 + 1) * 1024);
    };

    f32x4 acc[4][4];
#pragma unroll
    for (int mi = 0; mi < 4; ++mi)
#pragma unroll
        for (int ni = 0; ni < 4; ++ni) acc[mi][ni] = (f32x4){0.f, 0.f, 0.f, 0.f};

    STAGE(0, 0);
    __syncthreads();

    for (int kt = 0; kt < nt; ++kt) {
        const int buf = kt & 1;
        if (kt + 1 < nt) STAGE(kt + 1, buf ^ 1);
        bf16x8 af[4], bfr[4];
#pragma unroll
        for (int mi = 0; mi < 4; ++mi) {
            int row = wr * 64 + mi * 16 + frow;
            af[mi] = *(const bf16x8*)&As[buf][row * BK + kgrp * 8];
        }
#pragma unroll
        for (int ni = 0; ni < 4; ++ni) {
            int col = wc * 64 + ni * 16 + frow;
            bfr[ni] = *(const bf16x8*)&Bs[buf][col * BK + kgrp * 8];
        }
#pragma unroll
        for (int mi = 0; mi < 4; ++mi)
#pragma unroll
            for (int ni = 0; ni < 4; ++ni)
                acc[mi][ni] = __builtin_amdgcn_mfma_f32_16x16x32_bf16(
                    af[mi], bfr[ni], acc[mi][ni], 0, 0, 0);
        __syncthreads();
    }

    const size_t row0 = (size_t)bm * BM + wr * 64 + kgrp * 4;
    const int col0 = bn * BN + wc * 64 + frow;
    float* Cp = C + (size_t)bz * (size_t)sC;
#pragma unroll
    for (int mi = 0; mi < 4; ++mi)
#pragma unroll
        for (int r = 0; r < 4; ++r) {
            float* op = Cp + (row0 + mi * 16 + r) * N + col0;
#pragma unroll
            for (int ni = 0; ni < 4; ++ni) op[ni * 16] = acc[mi][ni][r];
        }
}

__global__ __launch_bounds__(256) void cvt_f32_bf16(
    const float* __restrict__ in, unsigned short* __restrict__ out, int n) {
    int idx = blockIdx.x * blockDim.x + threadIdx.x;
    int stride = gridDim.x * blockDim.x;
    for (int i = idx * 4; i < n; i += stride * 4) {
        float4 v = *(const float4*)(in + i);
        ushort4 o;
        o.x = f2bf(v.x); o.y = f2bf(v.y); o.z = f2bf(v.z); o.w = f2bf(v.w);
        *(ushort4*)(out + i) = o;
    }
}

// out[n][k] = (bf16) in[k][n];  in: [Kd][Nd] f32, batched over blockIdx.z
__global__ __launch_bounds__(256) void transpose_cvt_w(
    const float* __restrict__ in, unsigned short* __restrict__ out, int Kd, int Nd) {
    __shared__ float t[32][33];
    const int bz = blockIdx.z;
    in += (size_t)bz * Kd * Nd;
    out += (size_t)bz * Kd * Nd;
    const int tr = blockIdx.y * 32, tc = blockIdx.x * 32;
    const int r = threadIdx.x >> 3, c4 = (threadIdx.x & 7) * 4;
    float4 v = *(const float4*)&in[(size_t)(tr + r) * Nd + tc + c4];
    t[r][c4 + 0] = v.x; t[r][c4 + 1] = v.y; t[r][c4 + 2] = v.z; t[r][c4 + 3] = v.w;
    __syncthreads();
    ushort4 o;
    o.x = f2bf(t[c4 + 0][r]); o.y = f2bf(t[c4 + 1][r]);
    o.z = f2bf(t[c4 + 2][r]); o.w = f2bf(t[c4 + 3][r]);
    *(ushort4*)&out[(size_t)(tc + r) * Kd + tr + c4] = o;
}

// out[c][r] = in[r][c], bf16, batched by blockIdx.z
__global__ __launch_bounds__(256) void transpose_bf16(
    const unsigned short* __restrict__ in, unsigned short* __restrict__ out,
    int R, int Cc) {
    __shared__ unsigned short t[32][36];
    const int bz = blockIdx.z;
    in += (size_t)bz * R * Cc;
    out += (size_t)bz * R * Cc;
    const int tr = blockIdx.y * 32, tc = blockIdx.x * 32;
    const int r = threadIdx.x >> 3, c4 = (threadIdx.x & 7) * 4;
    ushort4 v = *(const ushort4*)&in[(size_t)(tr + r) * Cc + tc + c4];
    t[r][c4 + 0] = v.x; t[r][c4 + 1] = v.y; t[r][c4 + 2] = v.z; t[r][c4 + 3] = v.w;
    __syncthreads();
    ushort4 o;
    o.x = t[c4 + 0][r]; o.y = t[c4 + 1][r]; o.z = t[c4 + 2][r]; o.w = t[c4 + 3][r];
    *(ushort4*)&out[(size_t)(tc + r) * R + tr + c4] = o;
}

// In-place: read fp16 scores row, softmax over FULL row, causal-mask, write bf16 P.
__global__ __launch_bounds__(256) void softmax_mask(unsigned short* S, int Sd) {
    const int i = blockIdx.x;
    const int b = blockIdx.y;
    unsigned short* row = S + ((size_t)b * Sd + (size_t)i) * Sd;
    const int t = threadIdx.x;
    const int lane = t & 63, wid = t >> 6;

    ushort4 h0 = *(const ushort4*)(row + t * 8);
    ushort4 h1 = *(const ushort4*)(row + t * 8 + 4);
    float v[8];
    v[0] = __half2float(__ushort_as_half(h0.x));
    v[1] = __half2float(__ushort_as_half(h0.y));
    v[2] = __half2float(__ushort_as_half(h0.z));
    v[3] = __half2float(__ushort_as_half(h0.w));
    v[4] = __half2float(__ushort_as_half(h1.x));
    v[5] = __half2float(__ushort_as_half(h1.y));
    v[6] = __half2float(__ushort_as_half(h1.z));
    v[7] = __half2float(__ushort_as_half(h1.w));

    float m = v[0];
#pragma unroll
    for (int j = 1; j < 8; ++j) m = fmaxf(m, v[j]);
#pragma unroll
    for (int o = 32; o; o >>= 1) m = fmaxf(m, __shfl_xor(m, o));
    __shared__ float redm[4];
    __shared__ float reds[4];
    if (lane == 0) redm[wid] = m;
    __syncthreads();
    m = fmaxf(fmaxf(redm[0], redm[1]), fmaxf(redm[2], redm[3]));

    float e[8], s = 0.f;
#pragma unroll
    for (int j = 0; j < 8; ++j) {
        e[j] = __expf(v[j] - m);
        s += e[j];
    }
#pragma unroll
    for (int o = 32; o; o >>= 1) s += __shfl_xor(s, o);
    if (lane == 0) reds[wid] = s;
    __syncthreads();
    s = reds[0] + reds[1] + reds[2] + reds[3];
    const float rinv = 1.0f / s;

    const int base = t * 8;
    ushort4 o0, o1;
    o0.x = (base + 0 <= i) ? f2bf(e[0] * rinv) : 0;
    o0.y = (base + 1 <= i) ? f2bf(e[1] * rinv) : 0;
    o0.z = (base + 2 <= i) ? f2bf(e[2] * rinv) : 0;
    o0.w = (base + 3 <= i) ? f2bf(e[3] * rinv) : 0;
    o1.x = (base + 4 <= i) ? f2bf(e[4] * rinv) : 0;
    o1.y = (base + 5 <= i) ? f2bf(e[5] * rinv) : 0;
    o1.z = (base + 6 <= i) ? f2bf(e[6] * rinv) : 0;
    o1.w = (base + 7 <= i) ? f2bf(e[7] * rinv) : 0;
    *(ushort4*)(row + t * 8) = o0;
    *(ushort4*)(row + t * 8 + 4) = o1;
}

extern "C" void kernel_launch(void* const* d_in, const int* in_sizes, int n_in,
                              void* d_out, int out_size, void* d_ws, size_t ws_size,
                              hipStream_t stream) {
    const int B = 4, S = 2048, D = 1024;
    const size_t M = (size_t)B * S;  // 8192

    const float* x = (const float*)d_in[0];
    const float* Wq = (const float*)d_in[1];
    float* out = (float*)d_out;

    unsigned short* xb = (unsigned short*)d_ws;        // M*D
    unsigned short* Wt = xb + M * D;                   // 3*D*D
    unsigned short* Qb = Wt + 3 * (size_t)D * D;       // M*D
    unsigned short* Kb = Qb + M * D;                   // M*D
    unsigned short* Vb = Kb + M * D;                   // M*D
    unsigned short* Vt = Vb + M * D;                   // M*D
    unsigned short* Sc = Vt + M * D;                   // B*S*S
    const size_t need =
        (size_t)(M * D * 5 + 3 * (size_t)D * D + (size_t)B * S * S) * 2;
    if (ws_size < need) return;

    cvt_f32_bf16<<<2048, 256, 0, stream>>>(x, xb, (int)(M * D));
    // Wq,Wk,Wv are contiguous input pointers? No — separate. Launch batched over
    // a fake z by passing each base; they are distinct allocations, so launch 3.
    dim3 tg(D / 32, D / 32, 1);
    transpose_cvt_w<<<tg, 256, 0, stream>>>((const float*)d_in[1], Wt + 0 * (size_t)D * D, D, D);
    transpose_cvt_w<<<tg, 256, 0, stream>>>((const float*)d_in[2], Wt + 1 * (size_t)D * D, D, D);
    transpose_cvt_w<<<tg, 256, 0, stream>>>((const float*)d_in[3], Wt + 2 * (size_t)D * D, D, D);
    (void)Wq;

    // Q,K,V projections: 256^2 pipelined, z=3 over {Wq,Wk,Wv}; same A (strideA=0)
    gemm256<0><<<dim3(M / TBM, D / TBN, 3), 512, 0, stream>>>(
        xb, Wt, (void*)Qb, (int)M, D, D, 0LL, (long long)D * D, (long long)(M * D));

    transpose_bf16<<<dim3(D / 32, S / 32, B), 256, 0, stream>>>(Vb, Vt, S, D);

    // scores = Q K^T / 32 -> fp16 (256^2 pipelined)
    gemm256<2><<<dim3(S / TBM, S / TBN, B), 512, 0, stream>>>(
        Qb, Kb, (void*)Sc, S, S, D, (long long)S * D, (long long)S * D,
        (long long)S * S);

    softmax_mask<<<dim3(S, B), 256, 0, stream>>>(Sc, S);

    // context = P @ V  (A = P bf16, B = Vt[D][S]), causal K-tile skip
    gemm_bt_f32<<<dim3(S / BM, D / BN, B), 256, 0, stream>>>(
        Sc, Vt, out, S, D, S, (long long)S * S, (long long)D * S,
        (long long)S * D, 1);
}